// Round 12
// baseline (96.196 us; speedup 1.0000x reference)
//
#include <hip/hip_runtime.h>
#include <hip/hip_bf16.h>
#include <cmath>

// B=128, T=256, D=1024, V=32000, E=300
// d_out (floats): logits[0..4096000), h_new[4096000), c_new[4227072),
//                 attn[4358144), context[4390912), total 4521984

#define Bc 128
#define Tc 256
#define Dc 1024
#define Vc 32000
#define Ec 300
#define KREAL 2348        // D + E + D
#define KXP 2816          // padded: 4 splits x 11 steps x 64
#define KSPLIT 4
#define N4 4096

typedef __attribute__((ext_vector_type(8))) short bf16x8;
typedef __attribute__((ext_vector_type(4))) float f32x4;

static __device__ __forceinline__ short f2bf(float x) {
    __hip_bfloat16 b = __float2bfloat16(x);   // RNE
    return *reinterpret_cast<short*>(&b);
}
static __device__ __forceinline__ unsigned pack2(float a, float b) {
    return (unsigned)(unsigned short)f2bf(a) | ((unsigned)(unsigned short)f2bf(b) << 16);
}

// ---- A1 (single-pass): per (tc,b): scores + context partial for 64 t's. ----
__global__ void k_att1(const float* __restrict__ enc, const float* __restrict__ h,
                       float* __restrict__ scores_g, float* __restrict__ ctx_part) {
    const int tc = blockIdx.x;            // 0..3 (64-row chunk)
    const int b  = blockIdx.y;
    const int tid = threadIdx.x;
    const int wave = tid >> 6, lane = tid & 63;
    __shared__ float s_acc[4][1024];      // 16 KB

    const float4* h4 = (const float4*)(h + ((size_t)b << 10));
    float4 hv0 = h4[lane], hv1 = h4[lane + 64], hv2 = h4[lane + 128], hv3 = h4[lane + 192];

    float4 a0 = {0,0,0,0}, a1 = {0,0,0,0}, a2 = {0,0,0,0}, a3 = {0,0,0,0};
    const int t0 = (tc << 6) + (wave << 4);
    const float4* e4 = (const float4*)(enc + ((size_t)(b * Tc + t0) << 10));

    #pragma unroll 2
    for (int i = 0; i < 16; ++i) {
        float4 e0 = e4[lane], e1 = e4[lane + 64], e2 = e4[lane + 128], e3 = e4[lane + 192];
        e4 += 256;
        float d = e0.x*hv0.x + e0.y*hv0.y + e0.z*hv0.z + e0.w*hv0.w
                + e1.x*hv1.x + e1.y*hv1.y + e1.z*hv1.z + e1.w*hv1.w
                + e2.x*hv2.x + e2.y*hv2.y + e2.z*hv2.z + e2.w*hv2.w
                + e3.x*hv3.x + e3.y*hv3.y + e3.z*hv3.z + e3.w*hv3.w;
        #pragma unroll
        for (int off = 32; off; off >>= 1) d += __shfl_xor(d, off, 64);
        if (lane == 0) scores_g[(b << 8) + t0 + i] = d;
        a0.x += d*e0.x; a0.y += d*e0.y; a0.z += d*e0.z; a0.w += d*e0.w;
        a1.x += d*e1.x; a1.y += d*e1.y; a1.z += d*e1.z; a1.w += d*e1.w;
        a2.x += d*e2.x; a2.y += d*e2.y; a2.z += d*e2.z; a2.w += d*e2.w;
        a3.x += d*e3.x; a3.y += d*e3.y; a3.z += d*e3.z; a3.w += d*e3.w;
    }

    *(float4*)&s_acc[wave][lane << 2]         = a0;
    *(float4*)&s_acc[wave][256 + (lane << 2)] = a1;
    *(float4*)&s_acc[wave][512 + (lane << 2)] = a2;
    *(float4*)&s_acc[wave][768 + (lane << 2)] = a3;
    __syncthreads();
    float4 r0 = *(const float4*)&s_acc[0][tid << 2];
    float4 r1 = *(const float4*)&s_acc[1][tid << 2];
    float4 r2 = *(const float4*)&s_acc[2][tid << 2];
    float4 r3 = *(const float4*)&s_acc[3][tid << 2];
    float4 r;
    r.x = r0.x + r1.x + r2.x + r3.x;
    r.y = r0.y + r1.y + r2.y + r3.y;
    r.z = r0.z + r1.z + r2.z + r3.z;
    r.w = r0.w + r1.w + r2.w + r3.w;
    *(float4*)(ctx_part + (((size_t)(tc << 7) + b) << 10) + (tid << 2)) = r;
}

// ---- A2: reduce 4 ctx parts; softmax->attn; pack x_bf16 = [ctx, emb, h, 0] ----
__global__ void k_att2(const float* __restrict__ ctx_part, const float* __restrict__ scores_g,
                       const int* __restrict__ idx, const float* __restrict__ emb_table,
                       const float* __restrict__ h,
                       float* __restrict__ ctx_out, float* __restrict__ attn_out,
                       unsigned short* __restrict__ x_bf) {
    const int b = blockIdx.x;
    const int tid = threadIdx.x;
    __shared__ float red[256];

    float4 cv = {0.f, 0.f, 0.f, 0.f};
    #pragma unroll
    for (int tc = 0; tc < 4; ++tc) {
        float4 s = *(const float4*)(ctx_part + (((size_t)(tc << 7) + b) << 10) + (tid << 2));
        cv.x += s.x; cv.y += s.y; cv.z += s.z; cv.w += s.w;
    }
    *(float4*)(ctx_out + ((size_t)b << 10) + (tid << 2)) = cv;

    unsigned short* xb = x_bf + (size_t)b * KXP;
    uint2 p0; p0.x = pack2(cv.x, cv.y); p0.y = pack2(cv.z, cv.w);
    *(uint2*)&xb[tid << 2] = p0;

    int row = idx[b];
    for (int i = tid; i < Ec; i += 256)
        xb[Dc + i] = (unsigned short)f2bf(emb_table[(size_t)row * Ec + i]);

    float4 hv = *(const float4*)(h + ((size_t)b << 10) + (tid << 2));
    uint2 p1; p1.x = pack2(hv.x, hv.y); p1.y = pack2(hv.z, hv.w);
    *(uint2*)&xb[(Dc + Ec) + (tid << 2)] = p1;

    for (int i = tid; i < KXP - KREAL; i += 256) xb[KREAL + i] = 0;

    float v = scores_g[(b << 8) + tid];
    red[tid] = v;
    __syncthreads();
    for (int s = 128; s; s >>= 1) { if (tid < s) red[tid] = fmaxf(red[tid], red[tid + s]); __syncthreads(); }
    float m = red[0];
    __syncthreads();
    float e = __expf(v - m);
    red[tid] = e;
    __syncthreads();
    for (int s = 128; s; s >>= 1) { if (tid < s) red[tid] += red[tid + s]; __syncthreads(); }
    attn_out[(b << 8) + tid] = e / red[0];
}

// ---- Z: z partials, bf16 MFMA, K-step 64, reg-prefetch depth 3, LDS dbuf,
//      ONE barrier/step. grid (64,4) x 512. ----
__global__ __launch_bounds__(512) void k_zgemm_mfma(
        const unsigned short* __restrict__ xbf, const float* __restrict__ Wl,
        const float* __restrict__ Ul, float* __restrict__ z_part) {
    __shared__ __align__(16) short blds[2 * 8 * 64 * 8];   // 16 KB (2 bufs x 8 KB)
    const int tid  = threadIdx.x;
    const int wid  = tid >> 6;
    const int lane = tid & 63;
    const int g    = lane >> 4;
    const int r    = lane & 15;
    const int n0   = blockIdx.x << 6;     // 64-wide n tile
    const int ksp  = blockIdx.y;          // 0..3, steps ksp*11 .. +10
    const int kbase = ksp * 11;

    const int pr = tid >> 4;
    const int c  = tid & 15;
    const int kk = (pr << 1) & 31;
    const int gg = kk >> 3, jj = kk & 7;
    const int ks0 = pr >> 4;              // 0 or 1

    f32x4 acc[4] = {};
    const unsigned short* xrow = xbf + (size_t)((wid << 4) + r) * KXP;

    float4 wrA[3], wrB[3];
    bf16x8 areg[2][2];

    auto loadWU = [&](int gk) -> float4 {
        if (gk < 1324) return *(const float4*)(Wl + (size_t)gk * N4 + n0 + (c << 2));
        if (gk < KREAL) return *(const float4*)(Ul + (size_t)(gk - 1324) * N4 + n0 + (c << 2));
        return float4{0.f, 0.f, 0.f, 0.f};
    };

    // prologue: tiles 0,1,2 in flight; A-frag for tile 0
    #pragma unroll
    for (int p = 0; p < 3; ++p) {
        const int kt = (kbase + p) << 6;
        wrA[p] = loadWU(kt + (pr << 1));
        wrB[p] = loadWU(kt + (pr << 1) + 1);
    }
    {
        const int kt = kbase << 6;
        areg[0][0] = *(const bf16x8*)&xrow[kt + (g << 3)];
        areg[0][1] = *(const bf16x8*)&xrow[kt + 32 + (g << 3)];
    }

    #pragma unroll
    for (int t = 0; t < 11; ++t) {
        const int slot = t % 3;
        const int cur  = t & 1;
        const int coff = cur << 12;       // shorts
        // stage wr[slot] -> LDS[cur] (vmcnt wait covered by 2 prior iters)
        {
            const float av[4] = {wrA[slot].x, wrA[slot].y, wrA[slot].z, wrA[slot].w};
            const float bv[4] = {wrB[slot].x, wrB[slot].y, wrB[slot].z, wrB[slot].w};
            #pragma unroll
            for (int i = 0; i < 4; ++i) {
                int n = (c << 2) + i;
                int nt = n >> 4;
                int inner = (gg << 4) | (n & 15);
                int Xs = ((((ks0 << 2) + nt) << 6) | inner) ^ nt;
                *(unsigned*)&blds[coff + (Xs << 3) + jj] = pack2(av[i], bv[i]);
            }
        }
        // issue tile t+3 into freed slot
        if (t + 3 < 11) {
            const int kt = (kbase + t + 3) << 6;
            wrA[slot] = loadWU(kt + (pr << 1));
            wrB[slot] = loadWU(kt + (pr << 1) + 1);
        }
        // A prefetch for t+1
        if (t + 1 < 11) {
            const int kt = (kbase + t + 1) << 6;
            areg[cur ^ 1][0] = *(const bf16x8*)&xrow[kt + (g << 3)];
            areg[cur ^ 1][1] = *(const bf16x8*)&xrow[kt + 32 + (g << 3)];
        }
        __syncthreads();
        #pragma unroll
        for (int ks = 0; ks < 2; ++ks) {
            #pragma unroll
            for (int nt = 0; nt < 4; ++nt) {
                int Xs = ((((ks << 2) + nt) << 6) | lane) ^ nt;
                bf16x8 bfr = *(const bf16x8*)&blds[coff + (Xs << 3)];
                acc[nt] = __builtin_amdgcn_mfma_f32_16x16x32_bf16(areg[cur][ks], bfr, acc[nt], 0, 0, 0);
            }
        }
    }

    float* zp = z_part + ((size_t)ksp << 19);
    #pragma unroll
    for (int nt = 0; nt < 4; ++nt) {
        int col = n0 + (nt << 4) + r;
        #pragma unroll
        for (int j = 0; j < 4; ++j) {
            int rowm = (wid << 4) + (g << 2) + j;
            zp[((size_t)rowm << 12) + col] = acc[nt][j];
        }
    }
}

// ---- G: sum 4 partials + bias -> gates -> c_new, h_new, h_bf16 (float4) ----
__global__ void k_gates(const float* __restrict__ z_part, const float* __restrict__ b_lstm,
                        const float* __restrict__ c_in, float* __restrict__ h_new,
                        float* __restrict__ c_new, unsigned short* __restrict__ h_bf) {
    int i = blockIdx.x * 256 + threadIdx.x;    // < 32768 (each handles 4 d)
    int b = i >> 8, d4 = (i & 255) << 2;
    size_t base = ((size_t)b << 12) + d4;
    float4 zi = *(const float4*)(b_lstm + d4);
    float4 zf = *(const float4*)(b_lstm + d4 + 1024);
    float4 zg = *(const float4*)(b_lstm + d4 + 2048);
    float4 zo = *(const float4*)(b_lstm + d4 + 3072);
    #pragma unroll
    for (int ks = 0; ks < KSPLIT; ++ks) {
        const float* zp = z_part + ((size_t)ks << 19);
        float4 t;
        t = *(const float4*)(zp + base);        zi.x += t.x; zi.y += t.y; zi.z += t.z; zi.w += t.w;
        t = *(const float4*)(zp + base + 1024); zf.x += t.x; zf.y += t.y; zf.z += t.z; zf.w += t.w;
        t = *(const float4*)(zp + base + 2048); zg.x += t.x; zg.y += t.y; zg.z += t.z; zg.w += t.w;
        t = *(const float4*)(zp + base + 3072); zo.x += t.x; zo.y += t.y; zo.z += t.z; zo.w += t.w;
    }
    float4 cin = *(const float4*)(c_in + ((size_t)b << 10) + d4);
    float4 cn, hn;
    {
        float si = 1.f/(1.f+__expf(-zi.x)), sf = 1.f/(1.f+__expf(-zf.x)), so = 1.f/(1.f+__expf(-zo.x));
        cn.x = sf*cin.x + si*tanhf(zg.x); hn.x = so*tanhf(cn.x);
        si = 1.f/(1.f+__expf(-zi.y)); sf = 1.f/(1.f+__expf(-zf.y)); so = 1.f/(1.f+__expf(-zo.y));
        cn.y = sf*cin.y + si*tanhf(zg.y); hn.y = so*tanhf(cn.y);
        si = 1.f/(1.f+__expf(-zi.z)); sf = 1.f/(1.f+__expf(-zf.z)); so = 1.f/(1.f+__expf(-zo.z));
        cn.z = sf*cin.z + si*tanhf(zg.z); hn.z = so*tanhf(cn.z);
        si = 1.f/(1.f+__expf(-zi.w)); sf = 1.f/(1.f+__expf(-zf.w)); so = 1.f/(1.f+__expf(-zo.w));
        cn.w = sf*cin.w + si*tanhf(zg.w); hn.w = so*tanhf(cn.w);
    }
    *(float4*)(c_new + ((size_t)b << 10) + d4) = cn;
    *(float4*)(h_new + ((size_t)b << 10) + d4) = hn;
    uint2 hp; hp.x = pack2(hn.x, hn.y); hp.y = pack2(hn.z, hn.w);
    *(uint2*)&h_bf[((size_t)b << 10) + d4] = hp;
}

// ---- L: logits, bf16 MFMA, K-step 64, reg-prefetch depth 3, LDS dbuf,
//      ONE barrier/step. 500 blocks x 512. ----
__global__ __launch_bounds__(512) void k_logits_mfma(
        const unsigned short* __restrict__ hbf, const float* __restrict__ Wd,
        const float* __restrict__ bd, float* __restrict__ out) {
    __shared__ __align__(16) short blds[2 * 8 * 64 * 8];   // 16 KB (2 bufs x 8 KB)
    const int tid  = threadIdx.x;
    const int wid  = tid >> 6;
    const int lane = tid & 63;
    const int g    = lane >> 4;
    const int r    = lane & 15;
    const int n0   = blockIdx.x << 6;     // 64-wide n tile

    const int pr = tid >> 4;              // 0..31 -> rows 2pr, 2pr+1
    const int c  = tid & 15;              // 4 cols
    const int kk = (pr << 1) & 31;
    const int gg = kk >> 3, jj = kk & 7;
    const int ks0 = pr >> 4;              // 0 or 1

    f32x4 acc[4] = {};
    const unsigned short* hrow = hbf + ((size_t)((wid << 4) + r) << 10);
    const float* wbase = Wd + (size_t)(pr << 1) * Vc + n0 + (c << 2);

    float4 wrA[3], wrB[3];
    bf16x8 areg[2][2];

    // prologue: tiles 0,1,2 in flight; A-frag for tile 0
    #pragma unroll
    for (int p = 0; p < 3; ++p) {
        const float* w0 = wbase + (size_t)(p << 6) * Vc;
        wrA[p] = *(const float4*)(w0);
        wrB[p] = *(const float4*)(w0 + Vc);
    }
    areg[0][0] = *(const bf16x8*)&hrow[(g << 3)];
    areg[0][1] = *(const bf16x8*)&hrow[32 + (g << 3)];

    #pragma unroll
    for (int t = 0; t < 16; ++t) {
        const int slot = t % 3;
        const int cur  = t & 1;
        const int coff = cur << 12;       // shorts
        {
            const float av[4] = {wrA[slot].x, wrA[slot].y, wrA[slot].z, wrA[slot].w};
            const float bv[4] = {wrB[slot].x, wrB[slot].y, wrB[slot].z, wrB[slot].w};
            #pragma unroll
            for (int i = 0; i < 4; ++i) {
                int n = (c << 2) + i;
                int nt = n >> 4;
                int inner = (gg << 4) | (n & 15);
                int Xs = ((((ks0 << 2) + nt) << 6) | inner) ^ nt;
                *(unsigned*)&blds[coff + (Xs << 3) + jj] = pack2(av[i], bv[i]);
            }
        }
        if (t + 3 < 16) {
            const float* w0 = wbase + (size_t)((t + 3) << 6) * Vc;
            wrA[slot] = *(const float4*)(w0);
            wrB[slot] = *(const float4*)(w0 + Vc);
        }
        if (t + 1 < 16) {
            const int kt = (t + 1) << 6;
            areg[cur ^ 1][0] = *(const bf16x8*)&hrow[kt + (g << 3)];
            areg[cur ^ 1][1] = *(const bf16x8*)&hrow[kt + 32 + (g << 3)];
        }
        __syncthreads();
        #pragma unroll
        for (int ks = 0; ks < 2; ++ks) {
            #pragma unroll
            for (int nt = 0; nt < 4; ++nt) {
                int Xs = ((((ks << 2) + nt) << 6) | lane) ^ nt;
                bf16x8 bfr = *(const bf16x8*)&blds[coff + (Xs << 3)];
                acc[nt] = __builtin_amdgcn_mfma_f32_16x16x32_bf16(areg[cur][ks], bfr, acc[nt], 0, 0, 0);
            }
        }
    }

    #pragma unroll
    for (int nt = 0; nt < 4; ++nt) {
        int col = n0 + (nt << 4) + r;
        float bias = bd[col];
        #pragma unroll
        for (int j = 0; j < 4; ++j) {
            int row = (wid << 4) + (g << 2) + j;
            out[(size_t)row * Vc + col] = acc[nt][j] + bias;
        }
    }
}

extern "C" void kernel_launch(void* const* d_in, const int* in_sizes, int n_in,
                              void* d_out, int out_size, void* d_ws, size_t ws_size,
                              hipStream_t stream) {
    const int*   idx = (const int*)d_in[0];
    const float* enc = (const float*)d_in[1];
    const float* h   = (const float*)d_in[2];
    const float* c   = (const float*)d_in[3];
    const float* emb = (const float*)d_in[4];
    const float* Wl  = (const float*)d_in[5];
    const float* Ul  = (const float*)d_in[6];
    const float* bl  = (const float*)d_in[7];
    const float* Wd  = (const float*)d_in[8];
    const float* bd  = (const float*)d_in[9];

    float* out    = (float*)d_out;
    float* logits = out;                 // 4,096,000
    float* h_new  = out + 4096000;
    float* c_new  = out + 4227072;
    float* attn   = out + 4358144;
    float* ctx    = out + 4390912;

    // Scratch consumed BEFORE k_logits_mfma lives in the logits region;
    // anything k_logits_mfma READS lives in d_ws (it writes [0,4096000)).
    float*          ctx_part = out;                  // 4*131072 = 524,288
    float*          scores_g = out + 524288;         // 32,768 (ends 557,056)
    float*          z_part   = out;                  // 4*524,288 = 2,097,152
    unsigned short* x_bf16   = (unsigned short*)d_ws;            // 128*2816 = 360,448 shorts
    unsigned short* h_bf16   = (unsigned short*)d_ws + 360448;   // 131,072 shorts (983,040 B)

    hipLaunchKernelGGL(k_att1, dim3(4, 128), dim3(256), 0, stream, enc, h, scores_g, ctx_part);
    hipLaunchKernelGGL(k_att2, dim3(128), dim3(256), 0, stream, ctx_part, scores_g, idx, emb, h,
                       ctx, attn, x_bf16);
    hipLaunchKernelGGL(k_zgemm_mfma, dim3(64, KSPLIT), dim3(512), 0, stream, x_bf16, Wl, Ul, z_part);
    hipLaunchKernelGGL(k_gates, dim3(128), dim3(256), 0, stream, z_part, bl, c, h_new, c_new, h_bf16);
    hipLaunchKernelGGL(k_logits_mfma, dim3(500), dim3(512), 0, stream, h_bf16, Wd, bd, logits);
}